// Round 4
// baseline (111.680 us; speedup 1.0000x reference)
//
#include <hip/hip_runtime.h>
#include <hip/hip_bf16.h>

#define TOKENS 64
#define IN_F 8192
#define OUT_F 8192
#define CB 256

typedef _Float16 half8 __attribute__((ext_vector_type(8)));
typedef float f32x4 __attribute__((ext_vector_type(4)));

// ---------------------------------------------------------------------------
// Kernel 1: xh = FWHT(x * SU) * (1/sqrt(IN_F) * Wscale[0])  -> fp16, stored in
// MFMA-A-FRAGMENT ORDER (k2 A-load = 64 lanes x 16B contiguous):
//   xh_frag[((ks*4 + mt)*64 + quad*16 + l15)*8 + j]
//     = xh_row[mt*16 + l15][ks*32 + quad*8 + j]
// float4 global loads via bit-remapped element ownership:
//   e(r,t) = ((r>>2)<<10) | (t<<2) | (r&3)
// ---------------------------------------------------------------------------
__global__ __launch_bounds__(256) void k_fwht_in(const float* __restrict__ x,
                                                 const float* __restrict__ SU,
                                                 const float* __restrict__ Wscale,
                                                 _Float16* __restrict__ xh_frag)
{
    __shared__ float buf[256 * 33];
    __shared__ _Float16 xrowP[256 * 40];
    const int t    = threadIdx.x;
    const int lane = t & 63;
    const int w    = t >> 6;
    const int row  = blockIdx.x;

    float v[32];
    const float* xr = x + row * IN_F;
#pragma unroll
    for (int rh = 0; rh < 8; ++rh) {
        int base = (rh << 10) | (t << 2);
        float4 xv = *(const float4*)(xr + base);
        float4 sv = *(const float4*)(SU + base);
        v[rh * 4 + 0] = xv.x * sv.x;
        v[rh * 4 + 1] = xv.y * sv.y;
        v[rh * 4 + 2] = xv.z * sv.z;
        v[rh * 4 + 3] = xv.w * sv.w;
    }
#pragma unroll
    for (int h = 1; h < 32; h <<= 1) {
#pragma unroll
        for (int r = 0; r < 32; ++r) {
            if ((r & h) == 0) {
                float a = v[r], b = v[r + h];
                v[r] = a + b;
                v[r + h] = a - b;
            }
        }
    }
#pragma unroll
    for (int m = 1; m < 64; m <<= 1) {
        bool upper = (lane & m) != 0;
#pragma unroll
        for (int r = 0; r < 32; ++r) {
            float p = __shfl_xor(v[r], m, 64);
            v[r] = upper ? (p - v[r]) : (v[r] + p);
        }
    }
#pragma unroll
    for (int r = 0; r < 32; ++r) buf[t * 33 + r] = v[r];
    __syncthreads();
    {
        float s1 = (w & 1) ? -1.f : 1.f;
        float s2 = (w & 2) ? -1.f : 1.f;
        float s3 = s1 * s2;
#pragma unroll
        for (int r = 0; r < 32; ++r) {
            float a0 = buf[(0 * 64 + lane) * 33 + r];
            float a1 = buf[(1 * 64 + lane) * 33 + r];
            float a2 = buf[(2 * 64 + lane) * 33 + r];
            float a3 = buf[(3 * 64 + lane) * 33 + r];
            v[r] = a0 + s1 * a1 + s2 * a2 + s3 * a3;
        }
    }
    const float scale = 0.011048543456039806f * Wscale[0];  // 1/sqrt(8192)*Wscale
#pragma unroll
    for (int r = 0; r < 32; ++r) {
        int c = ((r >> 2) << 10) | (t << 2) | (r & 3);      // e(r,t)
        int idx = (c & 31) + (c >> 5) * 40;
        xrowP[idx] = (_Float16)(v[r] * scale);
    }
    __syncthreads();
    {
        const int mt  = row >> 4;
        const int l15 = row & 15;
        _Float16* base = xh_frag + ((size_t)(t * 4 + mt) * 64 + l15) * 8;
#pragma unroll
        for (int g = 0; g < 4; ++g) {
            half8 val = *(const half8*)&xrowP[t * 40 + g * 8];
            *(half8*)(base + g * 16 * 8) = val;
        }
    }
}

// ---------------------------------------------------------------------------
// Kernel 2 (R12): barrier-free fused dequant GEMM, occupancy-doubled.
// R11 post-mortem: barrier-free + u8-pack helped (112.6->110.8) but k2 still
// ~16us vs a ~9us chip-wide DS floor (131K random 16B codebook gathers are
// algorithm-invariant). Overlap was capped by residency: 512 blocks = 2/CU =
// 4 waves/SIMD. R12: halve n-group to 32 -> 1024 blocks = 256 n-groups x 4
// K-parts, wave tile M=64 x N=32 (2 nt). Decode volume / Qidxs HBM / y_part
// all invariant; acc 64->32 VGPR so __launch_bounds__(256,4) (<=128 VGPR)
// gives 4 blocks/CU = 8 waves/SIMD. A-fragment L2 traffic doubles (~256MB,
// ~7.4us at L2 BW) — below the DS floor, overlappable. s_setprio(1) around
// the MFMA cluster (waves desynced -> T5 prerequisite present).
// LDS: 4KB glds + 17KB uni = 21.4KB -> 4 blocks/CU = 85.6KB.
// ---------------------------------------------------------------------------
#define SQWW 17   // u32 words per staged row (16 + 1 pad)
__global__ __launch_bounds__(256, 4) void k_qgemm(const _Float16* __restrict__ xh_frag,
                                                  const int* __restrict__ Qidxs,
                                                  const float* __restrict__ grid,
                                                  float* __restrict__ y_part)
{
    __shared__ __align__(16) _Float16 glds[CB * 8];            // 4 KB fp16 codebook
    __shared__ __align__(16) unsigned int uni[4 * 64 * SQWW];  // 17408 B (red size)
    float* red = (float*)uni;

    const int tid  = threadIdx.x;
    const int lane = tid & 63;
    const int w    = tid >> 6;        // wave id -> K sub-chunk
    const int col  = lane & 15;
    const int quad = lane >> 4;
    const int g    = blockIdx.x >> 2; // n-group (256)
    const int p    = blockIdx.x & 3;  // K-part (4)
    const int n0   = g * 32;

    unsigned int* sqw = uni + w * (64 * SQWW);   // wave-private slice

    // ---- wave-private Qidxs staging: rows 0..31, int-cols w*64..w*64+63 ----
    // lane (col,quad), iter i: row = i*4+quad, cols col*4..col*4+3 (int4).
    // pack 4 idx -> u32; word sqw[row][col] bytes 0..3 = quads 0..3 of step col.
    {
        const int* qbase = Qidxs + (size_t)n0 * 1024 + p * 256 + w * 64 + col * 4;
#pragma unroll
        for (int i = 0; i < 8; ++i) {
            int r = i * 4 + quad;
            int4 vv = *(const int4*)(qbase + (size_t)r * 1024);
            unsigned int pk = (unsigned int)(vv.x & 255) |
                              ((unsigned int)(vv.y & 255) << 8) |
                              ((unsigned int)(vv.z & 255) << 16) |
                              ((unsigned int)(vv.w & 255) << 24);
            sqw[r * SQWW + col] = pk;
        }
    }
    // ---- codebook -> LDS fp16, per-wave redundant (benign same-value race) ----
    {
#pragma unroll
        for (int e = 0; e < 4; ++e) {
            int entry = lane + 64 * e;
            float4 g0 = *((const float4*)grid + entry * 2);
            float4 g1 = *((const float4*)grid + entry * 2 + 1);
            half8 hv;
            hv[0] = (_Float16)g0.x; hv[1] = (_Float16)g0.y;
            hv[2] = (_Float16)g0.z; hv[3] = (_Float16)g0.w;
            hv[4] = (_Float16)g1.x; hv[5] = (_Float16)g1.y;
            hv[6] = (_Float16)g1.z; hv[7] = (_Float16)g1.w;
            *(half8*)&glds[entry * 8] = hv;
        }
    }
    __asm__ volatile("s_waitcnt lgkmcnt(0)" ::: "memory");
    __builtin_amdgcn_sched_barrier(0);

    const int shq = quad * 8;

    // q-word read: step s, nt: sqw[(nt*16+col)][s]; 4-lane broadcast, no conflicts
#define QWREAD(dst, s_)                                              \
    {                                                                \
        dst[0] = sqw[(0 * 16 + col) * SQWW + (s_)];                  \
        dst[1] = sqw[(1 * 16 + col) * SQWW + (s_)];                  \
    }

    // A fragment base: global kstep Ks = p*64 + w*16 + s; frag (s,mt) at +(s*4+mt)*512
    const _Float16* abase = xh_frag + ((size_t)(p * 64 + w * 16) * 4 * 64 + lane) * 8;

    f32x4 acc[2][4] = {};   // [nt][mt]

    // ---- pipeline prologue ----
    unsigned int qw_c[2], qw_n[2];
    QWREAD(qw_c, 0);
    QWREAD(qw_n, 1);
    half8 b_c[2];
#pragma unroll
    for (int nt = 0; nt < 2; ++nt) {
        unsigned int q = (qw_c[nt] >> shq) & 255u;
        b_c[nt] = *(const half8*)&glds[q * 8];
    }
    half8 a_c[4], a_n[4];
#pragma unroll
    for (int mt = 0; mt < 4; ++mt) {
        a_c[mt] = *(const half8*)(abase + (size_t)(0 * 4 + mt) * 512);
        a_n[mt] = *(const half8*)(abase + (size_t)(1 * 4 + mt) * 512);
    }

#pragma unroll 4
    for (int s = 0; s < 16; ++s) {
        const int s2q = (s + 2 < 16 ? s + 2 : 15);
        unsigned int qw_nn[2];
        QWREAD(qw_nn, s2q);                              // q-words(s+2)
        half8 b_n[2], a_nn[4];
#pragma unroll
        for (int nt = 0; nt < 2; ++nt) {
            unsigned int q = (qw_n[nt] >> shq) & 255u;   // b(s+1)
            b_n[nt] = *(const half8*)&glds[q * 8];
        }
#pragma unroll
        for (int mt = 0; mt < 4; ++mt)
            a_nn[mt] = *(const half8*)(abase + (size_t)(s2q * 4 + mt) * 512); // a(s+2)
        __builtin_amdgcn_s_setprio(1);
#pragma unroll
        for (int nt = 0; nt < 2; ++nt)
#pragma unroll
            for (int mt = 0; mt < 4; ++mt)
                acc[nt][mt] = __builtin_amdgcn_mfma_f32_16x16x32_f16(
                    a_c[mt], b_c[nt], acc[nt][mt], 0, 0, 0);
        __builtin_amdgcn_s_setprio(0);
#pragma unroll
        for (int nt = 0; nt < 2; ++nt) { b_c[nt] = b_n[nt]; qw_n[nt] = qw_nn[nt]; }
#pragma unroll
        for (int mt = 0; mt < 4; ++mt) { a_c[mt] = a_n[mt]; a_n[mt] = a_nn[mt]; }
    }

    // ---- epilogue: per-nt chunked cross-wave reduce; red aliases staging ----
    // wave w writes only red[w] (= its own dead sqw slice); barriers per chunk.
    float* redw = red + w * (64 * SQWW);
    float* yp = y_part + (size_t)p * TOKENS * OUT_F;
#pragma unroll
    for (int nt = 0; nt < 2; ++nt) {
#pragma unroll
        for (int mt = 0; mt < 4; ++mt)
#pragma unroll
            for (int i = 0; i < 4; ++i) {
                int r = mt * 16 + quad * 4 + i;
                redw[r * SQWW + col] = acc[nt][mt][i];
            }
        __syncthreads();
#pragma unroll
        for (int j = 0; j < 4; ++j) {
            int idx = j * 256 + tid;     // 0..1023
            int rr = idx >> 4;           // token row 0..63
            int cc = idx & 15;           // col within chunk
            float s = (red[(0 * 64 + rr) * SQWW + cc] + red[(1 * 64 + rr) * SQWW + cc])
                    + (red[(2 * 64 + rr) * SQWW + cc] + red[(3 * 64 + rr) * SQWW + cc]);
            yp[(size_t)rr * OUT_F + n0 + nt * 16 + cc] = s;
        }
        __syncthreads();
    }
#undef QWREAD
}

// ---------------------------------------------------------------------------
// Kernel 3: fold 4 K-part partials, FWHT, * 1/sqrt(OUT_F) * SV + bias
// float4 loads/stores via the same e(r,t) bit remap as k1.
// ---------------------------------------------------------------------------
__global__ __launch_bounds__(256) void k_fwht_out(const float* __restrict__ y_part,
                                                  const float* __restrict__ SV,
                                                  const float* __restrict__ bias,
                                                  float* __restrict__ out)
{
    __shared__ float buf[256 * 33];
    const int t    = threadIdx.x;
    const int lane = t & 63;
    const int w    = t >> 6;
    const int row  = blockIdx.x;

    const float* y0 = y_part + (size_t)row * OUT_F;
    const size_t ps = (size_t)TOKENS * OUT_F;

    float v[32];
#pragma unroll
    for (int rh = 0; rh < 8; ++rh) {
        int base = (rh << 10) | (t << 2);
        float4 a = *(const float4*)(y0 + base);
        float4 b = *(const float4*)(y0 + ps + base);
        float4 c = *(const float4*)(y0 + 2 * ps + base);
        float4 d = *(const float4*)(y0 + 3 * ps + base);
        v[rh * 4 + 0] = (a.x + b.x) + (c.x + d.x);
        v[rh * 4 + 1] = (a.y + b.y) + (c.y + d.y);
        v[rh * 4 + 2] = (a.z + b.z) + (c.z + d.z);
        v[rh * 4 + 3] = (a.w + b.w) + (c.w + d.w);
    }
#pragma unroll
    for (int h = 1; h < 32; h <<= 1) {
#pragma unroll
        for (int r = 0; r < 32; ++r) {
            if ((r & h) == 0) {
                float a = v[r], b = v[r + h];
                v[r] = a + b;
                v[r + h] = a - b;
            }
        }
    }
#pragma unroll
    for (int m = 1; m < 64; m <<= 1) {
        bool upper = (lane & m) != 0;
#pragma unroll
        for (int r = 0; r < 32; ++r) {
            float p = __shfl_xor(v[r], m, 64);
            v[r] = upper ? (p - v[r]) : (v[r] + p);
        }
    }
#pragma unroll
    for (int r = 0; r < 32; ++r) buf[t * 33 + r] = v[r];
    __syncthreads();
    {
        float s1 = (w & 1) ? -1.f : 1.f;
        float s2 = (w & 2) ? -1.f : 1.f;
        float s3 = s1 * s2;
#pragma unroll
        for (int r = 0; r < 32; ++r) {
            float a0 = buf[(0 * 64 + lane) * 33 + r];
            float a1 = buf[(1 * 64 + lane) * 33 + r];
            float a2 = buf[(2 * 64 + lane) * 33 + r];
            float a3 = buf[(3 * 64 + lane) * 33 + r];
            v[r] = a0 + s1 * a1 + s2 * a2 + s3 * a3;
        }
    }
    const float scale = 0.011048543456039806f;  // 1/sqrt(8192)
    float* oo = out + (size_t)row * OUT_F;
#pragma unroll
    for (int rh = 0; rh < 8; ++rh) {
        int base = (rh << 10) | (t << 2);
        float4 sv = *(const float4*)(SV + base);
        float4 bv = *(const float4*)(bias + base);
        float4 o;
        o.x = v[rh * 4 + 0] * scale * sv.x + bv.x;
        o.y = v[rh * 4 + 1] * scale * sv.y + bv.y;
        o.z = v[rh * 4 + 2] * scale * sv.z + bv.z;
        o.w = v[rh * 4 + 3] * scale * sv.w + bv.w;
        *(float4*)(oo + base) = o;
    }
}

extern "C" void kernel_launch(void* const* d_in, const int* in_sizes, int n_in,
                              void* d_out, int out_size, void* d_ws, size_t ws_size,
                              hipStream_t stream) {
    const float* x      = (const float*)d_in[0];
    const float* SU     = (const float*)d_in[1];
    const float* SV     = (const float*)d_in[2];
    const float* grid   = (const float*)d_in[3];
    const float* Wscale = (const float*)d_in[4];
    const float* bias   = (const float*)d_in[5];
    const int*   Qidxs  = (const int*)d_in[6];
    float* out = (float*)d_out;

    // ws layout: xh_frag 1 MB | y_part 8 MB
    _Float16* xh_frag = (_Float16*)d_ws;
    float*    y_part  = (float*)((char*)d_ws + ((size_t)1 << 20));

    k_fwht_in<<<TOKENS, 256, 0, stream>>>(x, SU, Wscale, xh_frag);
    k_qgemm<<<1024, 256, 0, stream>>>(xh_frag, Qidxs, grid, y_part);
    k_fwht_out<<<TOKENS, 256, 0, stream>>>(y_part, SV, bias, out);
}

// Round 5
// 110.642 us; speedup vs baseline: 1.0094x; 1.0094x over previous
//
#include <hip/hip_runtime.h>
#include <hip/hip_bf16.h>

#define TOKENS 64
#define IN_F 8192
#define OUT_F 8192
#define CB 256

typedef _Float16 half8 __attribute__((ext_vector_type(8)));
typedef _Float16 half4v __attribute__((ext_vector_type(4)));
typedef float f32x4 __attribute__((ext_vector_type(4)));

// ---------------------------------------------------------------------------
// Kernel 1: xh = FWHT(x * SU) * (1/sqrt(IN_F) * Wscale[0])  -> fp16, stored in
// MFMA-A-FRAGMENT ORDER (k2 A-load = 64 lanes x 16B contiguous):
//   xh_frag[((ks*4 + mt)*64 + quad*16 + l15)*8 + j]
//     = xh_row[mt*16 + l15][ks*32 + quad*8 + j]
// float4 global loads via bit-remapped element ownership:
//   e(r,t) = ((r>>2)<<10) | (t<<2) | (r&3)
// ---------------------------------------------------------------------------
__global__ __launch_bounds__(256) void k_fwht_in(const float* __restrict__ x,
                                                 const float* __restrict__ SU,
                                                 const float* __restrict__ Wscale,
                                                 _Float16* __restrict__ xh_frag)
{
    __shared__ float buf[256 * 33];
    __shared__ _Float16 xrowP[256 * 40];
    const int t    = threadIdx.x;
    const int lane = t & 63;
    const int w    = t >> 6;
    const int row  = blockIdx.x;

    float v[32];
    const float* xr = x + row * IN_F;
#pragma unroll
    for (int rh = 0; rh < 8; ++rh) {
        int base = (rh << 10) | (t << 2);
        float4 xv = *(const float4*)(xr + base);
        float4 sv = *(const float4*)(SU + base);
        v[rh * 4 + 0] = xv.x * sv.x;
        v[rh * 4 + 1] = xv.y * sv.y;
        v[rh * 4 + 2] = xv.z * sv.z;
        v[rh * 4 + 3] = xv.w * sv.w;
    }
#pragma unroll
    for (int h = 1; h < 32; h <<= 1) {
#pragma unroll
        for (int r = 0; r < 32; ++r) {
            if ((r & h) == 0) {
                float a = v[r], b = v[r + h];
                v[r] = a + b;
                v[r + h] = a - b;
            }
        }
    }
#pragma unroll
    for (int m = 1; m < 64; m <<= 1) {
        bool upper = (lane & m) != 0;
#pragma unroll
        for (int r = 0; r < 32; ++r) {
            float p = __shfl_xor(v[r], m, 64);
            v[r] = upper ? (p - v[r]) : (v[r] + p);
        }
    }
#pragma unroll
    for (int r = 0; r < 32; ++r) buf[t * 33 + r] = v[r];
    __syncthreads();
    {
        float s1 = (w & 1) ? -1.f : 1.f;
        float s2 = (w & 2) ? -1.f : 1.f;
        float s3 = s1 * s2;
#pragma unroll
        for (int r = 0; r < 32; ++r) {
            float a0 = buf[(0 * 64 + lane) * 33 + r];
            float a1 = buf[(1 * 64 + lane) * 33 + r];
            float a2 = buf[(2 * 64 + lane) * 33 + r];
            float a3 = buf[(3 * 64 + lane) * 33 + r];
            v[r] = a0 + s1 * a1 + s2 * a2 + s3 * a3;
        }
    }
    const float scale = 0.011048543456039806f * Wscale[0];  // 1/sqrt(8192)*Wscale
#pragma unroll
    for (int r = 0; r < 32; ++r) {
        int c = ((r >> 2) << 10) | (t << 2) | (r & 3);      // e(r,t)
        int idx = (c & 31) + (c >> 5) * 40;
        xrowP[idx] = (_Float16)(v[r] * scale);
    }
    __syncthreads();
    {
        const int mt  = row >> 4;
        const int l15 = row & 15;
        _Float16* base = xh_frag + ((size_t)(t * 4 + mt) * 64 + l15) * 8;
#pragma unroll
        for (int g = 0; g < 4; ++g) {
            half8 val = *(const half8*)&xrowP[t * 40 + g * 8];
            *(half8*)(base + g * 16 * 8) = val;
        }
    }
}

// ---------------------------------------------------------------------------
// Kernel 2 (R13): barrier-free fused dequant GEMM = R11 base (best measured,
// 110.8 us) + full K-loop unroll (kills the ~40 v_mov/step of the 3-deep
// register rotation) + s_setprio around MFMA (waves desynced -> T5 regime)
// + fp16 y_part stores (partials ~N(0,45), fp16 err ~0.02 abs; -4MB HBM).
// R12 post-mortem: doubling blocks/CU (1024 blocks, nt=2) was a wash ->
// k2 is DS/VMEM-throughput-bound, not occupancy-bound. Revert to 512 blocks.
// Structure: wave-private u8-packed Qidxs staging (no barriers), 1-ds_read_b32
// q-broadcast, per-wave redundant codebook, red aliases staging in epilogue.
// LDS: 4KB glds + 17KB uni = 21.4KB, 2 blocks/CU.
// ---------------------------------------------------------------------------
#define SQWW 17   // u32 words per staged row (16 + 1 pad)
__global__ __launch_bounds__(256, 2) void k_qgemm(const _Float16* __restrict__ xh_frag,
                                                  const int* __restrict__ Qidxs,
                                                  const float* __restrict__ grid,
                                                  _Float16* __restrict__ y_part)
{
    __shared__ __align__(16) _Float16 glds[CB * 8];            // 4 KB fp16 codebook
    __shared__ __align__(16) unsigned int uni[4 * 64 * SQWW];  // 17408 B
    float* red = (float*)uni;

    const int tid  = threadIdx.x;
    const int lane = tid & 63;
    const int w    = tid >> 6;        // wave id -> K sub-chunk
    const int col  = lane & 15;
    const int quad = lane >> 4;
    const int g    = blockIdx.x >> 2; // n-group (128)
    const int p    = blockIdx.x & 3;  // K-part (4)
    const int n0   = g * 64;

    unsigned int* sqw = uni + w * (64 * SQWW);   // wave-private slice

    // ---- wave-private Qidxs staging: rows 0..63, int-cols w*64..w*64+63 ----
    // lane (col,quad), iter i: row = i*4+quad, cols col*4..col*4+3 (int4).
    // pack 4 idx -> u32; word sqw[row][col] bytes 0..3 = quads 0..3 of step col.
    {
        const int* qbase = Qidxs + (size_t)n0 * 1024 + p * 256 + w * 64 + col * 4;
#pragma unroll
        for (int i = 0; i < 16; ++i) {
            int r = i * 4 + quad;
            int4 vv = *(const int4*)(qbase + (size_t)r * 1024);
            unsigned int pk = (unsigned int)(vv.x & 255) |
                              ((unsigned int)(vv.y & 255) << 8) |
                              ((unsigned int)(vv.z & 255) << 16) |
                              ((unsigned int)(vv.w & 255) << 24);
            sqw[r * SQWW + col] = pk;
        }
    }
    // ---- codebook -> LDS fp16, per-wave redundant (benign same-value race) ----
    {
#pragma unroll
        for (int e = 0; e < 4; ++e) {
            int entry = lane + 64 * e;
            float4 g0 = *((const float4*)grid + entry * 2);
            float4 g1 = *((const float4*)grid + entry * 2 + 1);
            half8 hv;
            hv[0] = (_Float16)g0.x; hv[1] = (_Float16)g0.y;
            hv[2] = (_Float16)g0.z; hv[3] = (_Float16)g0.w;
            hv[4] = (_Float16)g1.x; hv[5] = (_Float16)g1.y;
            hv[6] = (_Float16)g1.z; hv[7] = (_Float16)g1.w;
            *(half8*)&glds[entry * 8] = hv;
        }
    }
    __asm__ volatile("s_waitcnt lgkmcnt(0)" ::: "memory");
    __builtin_amdgcn_sched_barrier(0);

    const int shq = quad * 8;

    // q-word read: step s, nt: sqw[(nt*16+col)][s]; 4-lane broadcast, no conflicts
#define QWREAD(dst, s_)                                              \
    {                                                                \
        dst[0] = sqw[(0 * 16 + col) * SQWW + (s_)];                  \
        dst[1] = sqw[(1 * 16 + col) * SQWW + (s_)];                  \
        dst[2] = sqw[(2 * 16 + col) * SQWW + (s_)];                  \
        dst[3] = sqw[(3 * 16 + col) * SQWW + (s_)];                  \
    }

    // A fragment base: global kstep Ks = p*64 + w*16 + s; frag (s,mt) at +(s*4+mt)*512
    const _Float16* abase = xh_frag + ((size_t)(p * 64 + w * 16) * 4 * 64 + lane) * 8;

    f32x4 acc[4][4] = {};   // [nt][mt]

    // ---- pipeline prologue ----
    unsigned int qw_c[4], qw_n[4];
    QWREAD(qw_c, 0);
    QWREAD(qw_n, 1);
    half8 b_c[4];
#pragma unroll
    for (int nt = 0; nt < 4; ++nt) {
        unsigned int q = (qw_c[nt] >> shq) & 255u;
        b_c[nt] = *(const half8*)&glds[q * 8];
    }
    half8 a_c[4], a_n[4];
#pragma unroll
    for (int mt = 0; mt < 4; ++mt) {
        a_c[mt] = *(const half8*)(abase + (size_t)(0 * 4 + mt) * 512);
        a_n[mt] = *(const half8*)(abase + (size_t)(1 * 4 + mt) * 512);
    }

#pragma unroll
    for (int s = 0; s < 16; ++s) {
        const int s2q = (s + 2 < 16 ? s + 2 : 15);
        unsigned int qw_nn[4];
        QWREAD(qw_nn, s2q);                              // q-words(s+2)
        half8 b_n[4], a_nn[4];
#pragma unroll
        for (int nt = 0; nt < 4; ++nt) {
            unsigned int q = (qw_n[nt] >> shq) & 255u;   // b(s+1)
            b_n[nt] = *(const half8*)&glds[q * 8];
        }
#pragma unroll
        for (int mt = 0; mt < 4; ++mt)
            a_nn[mt] = *(const half8*)(abase + (size_t)(s2q * 4 + mt) * 512); // a(s+2)
        __builtin_amdgcn_s_setprio(1);
#pragma unroll
        for (int nt = 0; nt < 4; ++nt)
#pragma unroll
            for (int mt = 0; mt < 4; ++mt)
                acc[nt][mt] = __builtin_amdgcn_mfma_f32_16x16x32_f16(
                    a_c[mt], b_c[nt], acc[nt][mt], 0, 0, 0);
        __builtin_amdgcn_s_setprio(0);
#pragma unroll
        for (int nt = 0; nt < 4; ++nt) { b_c[nt] = b_n[nt]; qw_n[nt] = qw_nn[nt]; }
#pragma unroll
        for (int mt = 0; mt < 4; ++mt) { a_c[mt] = a_n[mt]; a_n[mt] = a_nn[mt]; }
    }

    // ---- epilogue: per-nt chunked cross-wave reduce; red aliases staging ----
    // wave w writes only red[w] (= its own dead sqw slice); barriers per chunk.
    float* redw = red + w * (64 * SQWW);
    _Float16* yp = y_part + (size_t)p * TOKENS * OUT_F;
#pragma unroll
    for (int nt = 0; nt < 4; ++nt) {
#pragma unroll
        for (int mt = 0; mt < 4; ++mt)
#pragma unroll
            for (int i = 0; i < 4; ++i) {
                int r = mt * 16 + quad * 4 + i;
                redw[r * SQWW + col] = acc[nt][mt][i];
            }
        __syncthreads();
#pragma unroll
        for (int j = 0; j < 4; ++j) {
            int idx = j * 256 + tid;     // 0..1023
            int rr = idx >> 4;           // token row 0..63
            int cc = idx & 15;           // col within chunk
            float s = (red[(0 * 64 + rr) * SQWW + cc] + red[(1 * 64 + rr) * SQWW + cc])
                    + (red[(2 * 64 + rr) * SQWW + cc] + red[(3 * 64 + rr) * SQWW + cc]);
            yp[(size_t)rr * OUT_F + n0 + nt * 16 + cc] = (_Float16)s;
        }
        __syncthreads();
    }
#undef QWREAD
}

// ---------------------------------------------------------------------------
// Kernel 3: fold 4 fp16 K-part partials, FWHT, * 1/sqrt(OUT_F) * SV + bias
// float4 stores via the same e(r,t) bit remap as k1; 8B half4 part loads.
// ---------------------------------------------------------------------------
__global__ __launch_bounds__(256) void k_fwht_out(const _Float16* __restrict__ y_part,
                                                  const float* __restrict__ SV,
                                                  const float* __restrict__ bias,
                                                  float* __restrict__ out)
{
    __shared__ float buf[256 * 33];
    const int t    = threadIdx.x;
    const int lane = t & 63;
    const int w    = t >> 6;
    const int row  = blockIdx.x;

    const _Float16* y0 = y_part + (size_t)row * OUT_F;
    const size_t ps = (size_t)TOKENS * OUT_F;

    float v[32];
#pragma unroll
    for (int rh = 0; rh < 8; ++rh) {
        int base = (rh << 10) | (t << 2);
        half4v a = *(const half4v*)(y0 + base);
        half4v b = *(const half4v*)(y0 + ps + base);
        half4v c = *(const half4v*)(y0 + 2 * ps + base);
        half4v d = *(const half4v*)(y0 + 3 * ps + base);
#pragma unroll
        for (int q = 0; q < 4; ++q)
            v[rh * 4 + q] = ((float)a[q] + (float)b[q]) + ((float)c[q] + (float)d[q]);
    }
#pragma unroll
    for (int h = 1; h < 32; h <<= 1) {
#pragma unroll
        for (int r = 0; r < 32; ++r) {
            if ((r & h) == 0) {
                float a = v[r], b = v[r + h];
                v[r] = a + b;
                v[r + h] = a - b;
            }
        }
    }
#pragma unroll
    for (int m = 1; m < 64; m <<= 1) {
        bool upper = (lane & m) != 0;
#pragma unroll
        for (int r = 0; r < 32; ++r) {
            float p = __shfl_xor(v[r], m, 64);
            v[r] = upper ? (p - v[r]) : (v[r] + p);
        }
    }
#pragma unroll
    for (int r = 0; r < 32; ++r) buf[t * 33 + r] = v[r];
    __syncthreads();
    {
        float s1 = (w & 1) ? -1.f : 1.f;
        float s2 = (w & 2) ? -1.f : 1.f;
        float s3 = s1 * s2;
#pragma unroll
        for (int r = 0; r < 32; ++r) {
            float a0 = buf[(0 * 64 + lane) * 33 + r];
            float a1 = buf[(1 * 64 + lane) * 33 + r];
            float a2 = buf[(2 * 64 + lane) * 33 + r];
            float a3 = buf[(3 * 64 + lane) * 33 + r];
            v[r] = a0 + s1 * a1 + s2 * a2 + s3 * a3;
        }
    }
    const float scale = 0.011048543456039806f;  // 1/sqrt(8192)
    float* oo = out + (size_t)row * OUT_F;
#pragma unroll
    for (int rh = 0; rh < 8; ++rh) {
        int base = (rh << 10) | (t << 2);
        float4 sv = *(const float4*)(SV + base);
        float4 bv = *(const float4*)(bias + base);
        float4 o;
        o.x = v[rh * 4 + 0] * scale * sv.x + bv.x;
        o.y = v[rh * 4 + 1] * scale * sv.y + bv.y;
        o.z = v[rh * 4 + 2] * scale * sv.z + bv.z;
        o.w = v[rh * 4 + 3] * scale * sv.w + bv.w;
        *(float4*)(oo + base) = o;
    }
}

extern "C" void kernel_launch(void* const* d_in, const int* in_sizes, int n_in,
                              void* d_out, int out_size, void* d_ws, size_t ws_size,
                              hipStream_t stream) {
    const float* x      = (const float*)d_in[0];
    const float* SU     = (const float*)d_in[1];
    const float* SV     = (const float*)d_in[2];
    const float* grid   = (const float*)d_in[3];
    const float* Wscale = (const float*)d_in[4];
    const float* bias   = (const float*)d_in[5];
    const int*   Qidxs  = (const int*)d_in[6];
    float* out = (float*)d_out;

    // ws layout: xh_frag 1 MB | y_part (fp16) 4 MB
    _Float16* xh_frag = (_Float16*)d_ws;
    _Float16* y_part  = (_Float16*)((char*)d_ws + ((size_t)1 << 20));

    k_fwht_in<<<TOKENS, 256, 0, stream>>>(x, SU, Wscale, xh_frag);
    k_qgemm<<<512, 256, 0, stream>>>(xh_frag, Qidxs, grid, y_part);
    k_fwht_out<<<TOKENS, 256, 0, stream>>>(y_part, SV, bias, out);
}